// Round 4
// baseline (399.848 us; speedup 1.0000x reference)
//
#include <hip/hip_runtime.h>
#include <cstdint>
#include <cstddef>

// ---------- bf16 helpers (bit-level) ----------
__device__ __forceinline__ float bf2f(uint16_t u) {
    union { uint32_t i; float f; } w; w.i = ((uint32_t)u) << 16; return w.f;
}
__device__ __forceinline__ uint16_t f2bf(float f) {
    union { float f; uint32_t i; } w; w.f = f;
    uint32_t x = w.i;
    uint32_t r = (x + 0x7FFFu + ((x >> 16) & 1u)) >> 16;   // RNE
    return (uint16_t)r;
}

typedef __bf16 bf16x8 __attribute__((ext_vector_type(8)));
typedef float  f32x4  __attribute__((ext_vector_type(4)));

// async global->LDS, 16B per lane; LDS dest is wave-uniform base + lane*16
__device__ __forceinline__ void load_lds16(const void* gptr, void* lptr) {
    __builtin_amdgcn_global_load_lds(
        (__attribute__((address_space(1))) void*)gptr,
        (__attribute__((address_space(3))) void*)lptr,
        16, 0, 0);
}

// ---------- bf16 GEMM: C[M,N] = act(A[M,K] @ BT[N,K]^T + bias) ----------
// A, BT always bf16 (global_load_lds staging). Output fp32 or bf16.
// SPLIT: column blocks with gn0 >= ncut are routed to C2 (bf16, no bias).
// XCD swizzle: each XCD owns an M-slice (y-fastest order) so its 4MB L2
// holds the A-slice while B streams. Requires total blocks %8==0,
// 8%nz==0, ny%(8/nz)==0.
template<int OUTFP32, int RELU, int SPLIT>
__global__ __launch_bounds__(256, 3)
void gemm_bt(const uint16_t* __restrict__ A, const uint16_t* __restrict__ BT,
             const float* __restrict__ bias, void* __restrict__ Cv,
             int K, int lda, int ldb, int ldc,
             long long sA, long long sB, long long sC,
             void* __restrict__ C2v, int ldc2, int ncut)
{
    __shared__ uint16_t As[128 * 32];
    __shared__ uint16_t Bs[128 * 32];

    // ---- XCD swizzle ----
    const int nx = (int)gridDim.x, ny = (int)gridDim.y, nz = (int)gridDim.z;
    const int g   = (int)blockIdx.x + nx * ((int)blockIdx.y + ny * (int)blockIdx.z);
    const int xcd = g & 7;
    const int ii  = g >> 3;
    const int xz  = 8 / nz;          // XCDs per batch
    const int bz  = xcd / xz;
    const int sub = xcd % xz;
    const int ypc = ny / xz;         // y-blocks per XCD
    const int by  = sub * ypc + ii % ypc;
    const int bx  = ii / ypc;

    const int t    = threadIdx.x;
    const int lane = t & 63;
    const int w    = t >> 6;
    const int quad = lane >> 4;
    const int l15  = lane & 15;
    const int wr   = w >> 1;
    const int wc   = w & 1;
    const int gm0  = by * 128;
    const int gn0  = bx * 128;

    A  += (long long)bz * sA;
    BT += (long long)bz * sB;

    f32x4 acc[4][4] = {};

    const int ch_r = lane >> 2;        // row within 16-row chunk
    const int ch_c = (lane & 3) * 8;   // bf16 col offset (16B)

    for (int k0 = 0; k0 < K; k0 += 32) {
        __syncthreads();
        {
            int row = w * 16 + ch_r;
            load_lds16(BT + (size_t)(gn0 + row) * ldb + k0 + ch_c, (void*)(Bs + w * 512));
            load_lds16(BT + (size_t)(gn0 + row + 64) * ldb + k0 + ch_c, (void*)(Bs + (w + 4) * 512));
            load_lds16(A + (size_t)(gm0 + row) * lda + k0 + ch_c, (void*)(As + w * 512));
            load_lds16(A + (size_t)(gm0 + row + 64) * lda + k0 + ch_c, (void*)(As + (w + 4) * 512));
        }
        __syncthreads();

        bf16x8 af[4], bfr[4];
#pragma unroll
        for (int i = 0; i < 4; i++) {
            af[i]  = *(const bf16x8*)(As + (wr * 64 + i * 16 + l15) * 32 + quad * 8);
            bfr[i] = *(const bf16x8*)(Bs + (wc * 64 + i * 16 + l15) * 32 + quad * 8);
        }
#pragma unroll
        for (int mi = 0; mi < 4; mi++)
#pragma unroll
            for (int ni = 0; ni < 4; ni++)
                acc[mi][ni] = __builtin_amdgcn_mfma_f32_16x16x32_bf16(af[mi], bfr[ni], acc[mi][ni], 0, 0, 0);
    }

    // epilogue: C/D layout col=lane&15, row=quad*4+reg
    const bool to2 = SPLIT && (gn0 >= ncut);
#pragma unroll
    for (int ni = 0; ni < 4; ni++) {
        const int gcol = gn0 + wc * 64 + ni * 16 + l15;
        const float bv = (!to2 && bias) ? bias[gcol] : 0.0f;
#pragma unroll
        for (int mi = 0; mi < 4; mi++) {
#pragma unroll
            for (int r = 0; r < 4; r++) {
                const int grow = gm0 + wr * 64 + mi * 16 + quad * 4 + r;
                float v = acc[mi][ni][r] + bv;
                if (RELU) v = fmaxf(v, 0.0f);
                if (to2) {
                    uint16_t* C2 = (uint16_t*)C2v;
                    C2[(size_t)grow * ldc2 + (gcol - ncut)] = f2bf(v);
                } else if (OUTFP32) {
                    float* C = (float*)Cv + (long long)bz * sC;
                    C[(size_t)grow * ldc + gcol] = v;
                } else {
                    uint16_t* C = (uint16_t*)Cv + (long long)bz * sC;
                    C[(size_t)grow * ldc + gcol] = f2bf(v);
                }
            }
        }
    }
}

// ---------- flat cast fp32 -> bf16, 8 elems/thread ----------
__global__ __launch_bounds__(256)
void cast_f32_bf16(const float* __restrict__ src, uint16_t* __restrict__ dst)
{
    const size_t i = ((size_t)blockIdx.x * 256 + threadIdx.x) * 8;
    float4 f0 = *(const float4*)(src + i);
    float4 f1 = *(const float4*)(src + i + 4);
    uint16_t u[8];
    u[0] = f2bf(f0.x); u[1] = f2bf(f0.y); u[2] = f2bf(f0.z); u[3] = f2bf(f0.w);
    u[4] = f2bf(f1.x); u[5] = f2bf(f1.y); u[6] = f2bf(f1.z); u[7] = f2bf(f1.w);
    *(uint4*)(dst + i) = *(const uint4*)u;
}

// ---------- 2D strided cast fp32 -> bf16 (slice of wide matrix) ----------
// dst [R][C] (ld C) = src[r*src_ld + c], 8 elems/thread, C % 8 == 0
__global__ __launch_bounds__(256)
void cast2d_f32_bf16(const float* __restrict__ src, uint16_t* __restrict__ dst,
                     int src_ld, int C)
{
    const size_t i = ((size_t)blockIdx.x * 256 + threadIdx.x) * 8;
    const int r = (int)(i / C), c = (int)(i % C);
    const float* sp = src + (size_t)r * src_ld + c;
    float4 f0 = *(const float4*)sp;
    float4 f1 = *(const float4*)(sp + 4);
    uint16_t u[8];
    u[0] = f2bf(f0.x); u[1] = f2bf(f0.y); u[2] = f2bf(f0.z); u[3] = f2bf(f0.w);
    u[4] = f2bf(f1.x); u[5] = f2bf(f1.y); u[6] = f2bf(f1.z); u[7] = f2bf(f1.w);
    *(uint4*)(dst + i) = *(const uint4*)u;
}

// ---------- transpose fp32 -> bf16: dst[n][k] = bf16(src[k][n]) ----------
__global__ __launch_bounds__(256)
void transpose_f32_to_bf16(const float* __restrict__ src, uint16_t* __restrict__ dst,
                           int src_ld, int dst_ld)
{
    __shared__ uint16_t tile[64 * 65];
    const int k0 = blockIdx.y * 64, n0 = blockIdx.x * 64;
    const int t = threadIdx.x;
#pragma unroll
    for (int i = 0; i < 16; i++) {
        int idx = i * 256 + t;
        int r = idx >> 6, c = idx & 63;
        tile[c * 65 + r] = f2bf(src[(size_t)(k0 + r) * src_ld + n0 + c]);
    }
    __syncthreads();
#pragma unroll
    for (int i = 0; i < 16; i++) {
        int idx = i * 256 + t;
        int n = idx >> 6, k = idx & 63;
        dst[(size_t)(n0 + n) * dst_ld + k0 + k] = tile[n * 65 + k];
    }
}

// ---------- transpose bf16 -> bf16 (batched) ----------
__global__ __launch_bounds__(256)
void transpose_bf16(const uint16_t* __restrict__ src, uint16_t* __restrict__ dst,
                    int src_ld, int dst_ld, long long sS, long long sD)
{
    __shared__ uint16_t tile[64 * 65];
    src += (long long)blockIdx.z * sS;
    dst += (long long)blockIdx.z * sD;
    const int k0 = blockIdx.y * 64, n0 = blockIdx.x * 64;
    const int t = threadIdx.x;
#pragma unroll
    for (int i = 0; i < 16; i++) {
        int idx = i * 256 + t;
        int r = idx >> 6, c = idx & 63;
        tile[c * 65 + r] = src[(size_t)(k0 + r) * src_ld + n0 + c];
    }
    __syncthreads();
#pragma unroll
    for (int i = 0; i < 16; i++) {
        int idx = i * 256 + t;
        int n = idx >> 6, k = idx & 63;
        dst[(size_t)(n0 + n) * dst_ld + k0 + k] = tile[n * 65 + k];
    }
}

// ---------- bias_s[l] = sum_d b2[d] * D2L[d*4096 + l]  (fp32, l < 2048) ----------
__global__ __launch_bounds__(256)
void colbias(const float* __restrict__ b2, const float* __restrict__ D2L,
             float* __restrict__ out)
{
    const int l = blockIdx.x * 256 + threadIdx.x;
    float acc = 0.f;
#pragma unroll 8
    for (int d = 0; d < 1024; d++)
        acc = fmaf(b2[d], D2L[(size_t)d * 4096 + l], acc);
    out[l] = acc;
}

// ---------- masked softmax: read bf16 scores + fp32 colbias,
//            write fp32 attention (d_out) + bf16 attention (in-place) ----------
__global__ __launch_bounds__(256)
void softmax_rows(const uint16_t* __restrict__ Sin_, float* __restrict__ Aout,
                  uint16_t* __restrict__ Abf, const float* __restrict__ bs,
                  const int* __restrict__ mask, int L)
{
    const int row = blockIdx.x;
    const int b = row >> 11;                 // L == 2048
    const uint16_t* sp = Sin_ + (size_t)row * L;
    float* op = Aout + (size_t)row * L;
    uint16_t* bp = Abf + (size_t)row * L;
    const int* mrow = mask + (size_t)b * L;
    const int t = threadIdx.x;
    const int c0 = t * 8;

    uint16_t su[8];
    *(uint4*)su = *(const uint4*)(sp + c0);
    float v[8];
    bool mk[8];
    float lmax = -1e30f;
#pragma unroll
    for (int j = 0; j < 8; j++) {
        mk[j] = (mrow[c0 + j] != 0);
        v[j] = bf2f(su[j]) + bs[c0 + j];
        if (mk[j]) lmax = fmaxf(lmax, v[j]);
    }
#pragma unroll
    for (int off = 32; off > 0; off >>= 1)
        lmax = fmaxf(lmax, __shfl_xor(lmax, off, 64));

    __shared__ float redm[4];
    __shared__ float reds[4];
    const int w = t >> 6, lane = t & 63;
    if (lane == 0) redm[w] = lmax;
    __syncthreads();
    lmax = fmaxf(fmaxf(redm[0], redm[1]), fmaxf(redm[2], redm[3]));

    float e[8];
    float lsum = 0.f;
#pragma unroll
    for (int j = 0; j < 8; j++) {
        e[j] = mk[j] ? __expf(v[j] - lmax) : 0.0f;
        lsum += e[j];
    }
#pragma unroll
    for (int off = 32; off > 0; off >>= 1)
        lsum += __shfl_xor(lsum, off, 64);
    if (lane == 0) reds[w] = lsum;
    __syncthreads();
    lsum = reds[0] + reds[1] + reds[2] + reds[3];

    const float inv = 1.0f / lsum;
    uint16_t ub[8];
#pragma unroll
    for (int j = 0; j < 8; j++) {
        v[j] = e[j] * inv;
        ub[j] = f2bf(v[j]);
    }
    *(float4*)(op + c0)     = *(const float4*)(v + 0);
    *(float4*)(op + c0 + 4) = *(const float4*)(v + 4);
    *(uint4*)(bp + c0)      = *(const uint4*)ub;
}

extern "C" void kernel_launch(void* const* d_in, const int* in_sizes, int n_in,
                              void* d_out, int out_size, void* d_ws, size_t ws_size,
                              hipStream_t stream)
{
    const float* x    = (const float*)d_in[0];  // [4,2048,1024]
    const int*   mask = (const int*)d_in[1];    // [4,1,2048]
    const float* W1   = (const float*)d_in[2];  // [1024,1024]
    const float* b1   = (const float*)d_in[3];  // [1024]
    const float* W2   = (const float*)d_in[4];  // [1024,2048]
    const float* b2   = (const float*)d_in[5];  // [2048]
    const float* D2L  = (const float*)d_in[6];  // [1024,4096]

    const int Lr = 2048, D = 1024, M = 4 * Lr;  // 8192
    float* outp = (float*)d_out;                // [8192][1024] fp32
    float* attn = outp + (size_t)M * D;         // [8192][2048] fp32

    // ws layout (bytes): all 2B elems unless noted
    uint16_t* W1T    = (uint16_t*)d_ws;                  // 1024*1024      (2MB)
    uint16_t* BTcat  = W1T   + 1024 * 1024;              // 3072*1024      (6MB)  [0:1024)=W2vT, [1024:3072)=W2DT
    uint16_t* D2LT   = BTcat + 3072 * 1024;              // 2048*1024      (4MB)
    uint16_t* W2kbf  = D2LT  + 2048 * 1024;              // 1024*1024      (2MB)
    float*    bias_s = (float*)(W2kbf + 1024 * 1024);    // 2048 fp32      (8KB)
    uint16_t* xbf    = (uint16_t*)(bias_s + 2048);       // 8192*1024      (16MB)  -> reused as nothing
    uint16_t* hbuf   = xbf  + (size_t)M * D;             // 8192*1024      (16MB)  -> reused as vT
    uint16_t* Vbuf   = hbuf + (size_t)M * D;             // 8192*1024      (16MB)
    uint16_t* Sbf    = Vbuf + (size_t)M * D;             // 8192*2048      (32MB)
    uint16_t* vT     = Sbf  + (size_t)M * 2048;          // 4*1024*2048    (16MB)  total ~94MB

    dim3 blk(256);

    // casts / transposes of inputs
    cast_f32_bf16<<<dim3(4096), blk, 0, stream>>>(x, xbf);                          // x -> bf16
    transpose_f32_to_bf16<<<dim3(16, 16), blk, 0, stream>>>(W1, W1T, 1024, 1024);   // W1^T
    transpose_f32_to_bf16<<<dim3(16, 16), blk, 0, stream>>>(W2 + 1024, BTcat, 2048, 1024); // W2v^T
    transpose_f32_to_bf16<<<dim3(32, 16), blk, 0, stream>>>(D2L, D2LT, 4096, 1024); // D2L[:, :2048]^T
    cast2d_f32_bf16<<<dim3(512), blk, 0, stream>>>(W2, W2kbf, 2048, 1024);          // W2[:, :1024] bf16
    colbias<<<dim3(8), blk, 0, stream>>>(b2, D2L, bias_s);                          // b2[:1024] @ D2L

    // W2DT[l,e] = sum_d D2LT[l,d] * W2k[e,d]  -> BTcat rows 1024..3071
    gemm_bt<0, 0, 0><<<dim3(8, 16, 1), blk, 0, stream>>>(D2LT, W2kbf, nullptr,
        BTcat + 1024 * 1024, 1024, 1024, 1024, 1024, 0, 0, 0, nullptr, 0, 0);

    // h = relu(x @ W1 + b1)  [8192,1024] K=1024
    gemm_bt<0, 1, 0><<<dim3(8, 64, 1), blk, 0, stream>>>(xbf, W1T, b1, hbuf,
        1024, 1024, 1024, 1024, 0, 0, 0, nullptr, 0, 0);

    // fused: [v | scores] = h @ BTcat^T, N=3072; v->Vbuf(+b2v), scores->Sbf (bias later)
    gemm_bt<0, 0, 1><<<dim3(24, 64, 1), blk, 0, stream>>>(hbuf, BTcat, b2 + 1024, Vbuf,
        1024, 1024, 1024, 1024, 0, 0, 0, Sbf, 2048, 1024);

    // vT[b][d][m] = v[b][m][d]
    transpose_bf16<<<dim3(16, 32, 4), blk, 0, stream>>>(Vbuf, vT,
        1024, 2048, (long long)2048 * 1024, (long long)1024 * 2048);

    // softmax: bf16 scores + fp32 bias_s -> fp32 attn (d_out) + bf16 attn (in-place Sbf)
    softmax_rows<<<dim3(8192), blk, 0, stream>>>(Sbf, attn, Sbf, bias_s, mask, Lr);

    // output = attn @ v (batched), K=2048
    gemm_bt<1, 0, 0><<<dim3(8, 16, 4), blk, 0, stream>>>(Sbf, vT, nullptr, outp,
        2048, 2048, 2048, 1024,
        (long long)2048 * 2048, (long long)1024 * 2048, (long long)2048 * 1024,
        nullptr, 0, 0);
}

// Round 5
// 385.258 us; speedup vs baseline: 1.0379x; 1.0379x over previous
//
#include <hip/hip_runtime.h>
#include <cstdint>
#include <cstddef>

// ---------- bf16 helpers (bit-level) ----------
__device__ __forceinline__ float bf2f(uint16_t u) {
    union { uint32_t i; float f; } w; w.i = ((uint32_t)u) << 16; return w.f;
}
__device__ __forceinline__ uint16_t f2bf(float f) {
    union { float f; uint32_t i; } w; w.f = f;
    uint32_t x = w.i;
    uint32_t r = (x + 0x7FFFu + ((x >> 16) & 1u)) >> 16;   // RNE
    return (uint16_t)r;
}

typedef __bf16 bf16x8 __attribute__((ext_vector_type(8)));
typedef float  f32x4  __attribute__((ext_vector_type(4)));

// async global->LDS, 16B per lane; LDS dest is wave-uniform base + lane*16
__device__ __forceinline__ void load_lds16(const void* gptr, void* lptr) {
    __builtin_amdgcn_global_load_lds(
        (__attribute__((address_space(1))) void*)gptr,
        (__attribute__((address_space(3))) void*)lptr,
        16, 0, 0);
}

// ---------- bf16 GEMM: C[M,N] = act(A[M,K] @ BT[N,K]^T + bias) ----------
// BK=64 built from two BK=32 panels (keeps m97 LDS layout per panel,
// halves barrier drains: 32 MFMA per __syncthreads pair).
// XCD swizzle: each XCD owns an M-slice (y-fastest order). Requires
// total blocks %8==0, 8%nz==0, ny%(8/nz)==0. K % 64 == 0.
template<int OUTFP32, int RELU>
__global__ __launch_bounds__(256, 3)
void gemm_bt(const uint16_t* __restrict__ A, const uint16_t* __restrict__ BT,
             const float* __restrict__ bias, void* __restrict__ Cv,
             int K, int lda, int ldb, int ldc,
             long long sA, long long sB, long long sC)
{
    __shared__ uint16_t As[2][128 * 32];
    __shared__ uint16_t Bs[2][128 * 32];

    // ---- XCD swizzle ----
    const int nx = (int)gridDim.x, ny = (int)gridDim.y, nz = (int)gridDim.z;
    const int g   = (int)blockIdx.x + nx * ((int)blockIdx.y + ny * (int)blockIdx.z);
    const int xcd = g & 7;
    const int ii  = g >> 3;
    const int xz  = 8 / nz;          // XCDs per batch
    const int bz  = xcd / xz;
    const int sub = xcd % xz;
    const int ypc = ny / xz;         // y-blocks per XCD
    const int by  = sub * ypc + ii % ypc;
    const int bx  = ii / ypc;

    const int t    = threadIdx.x;
    const int lane = t & 63;
    const int w    = t >> 6;
    const int quad = lane >> 4;
    const int l15  = lane & 15;
    const int wr   = w >> 1;
    const int wc   = w & 1;
    const int gm0  = by * 128;
    const int gn0  = bx * 128;

    A  += (long long)bz * sA;
    BT += (long long)bz * sB;

    f32x4 acc[4][4] = {};

    const int ch_r = lane >> 2;        // row within 16-row chunk
    const int ch_c = (lane & 3) * 8;   // bf16 col offset (16B)

    for (int k0 = 0; k0 < K; k0 += 64) {
        __syncthreads();
        {
            const int row = w * 16 + ch_r;
            const size_t bo0 = (size_t)(gn0 + row) * ldb + k0 + ch_c;
            const size_t bo1 = (size_t)(gn0 + row + 64) * ldb + k0 + ch_c;
            const size_t ao0 = (size_t)(gm0 + row) * lda + k0 + ch_c;
            const size_t ao1 = (size_t)(gm0 + row + 64) * lda + k0 + ch_c;
            load_lds16(BT + bo0,      (void*)(Bs[0] + w * 512));
            load_lds16(BT + bo1,      (void*)(Bs[0] + (w + 4) * 512));
            load_lds16(BT + bo0 + 32, (void*)(Bs[1] + w * 512));
            load_lds16(BT + bo1 + 32, (void*)(Bs[1] + (w + 4) * 512));
            load_lds16(A + ao0,       (void*)(As[0] + w * 512));
            load_lds16(A + ao1,       (void*)(As[0] + (w + 4) * 512));
            load_lds16(A + ao0 + 32,  (void*)(As[1] + w * 512));
            load_lds16(A + ao1 + 32,  (void*)(As[1] + (w + 4) * 512));
        }
        __syncthreads();

#pragma unroll
        for (int s = 0; s < 2; s++) {
            bf16x8 af[4], bfr[4];
#pragma unroll
            for (int i = 0; i < 4; i++) {
                af[i]  = *(const bf16x8*)(As[s] + (wr * 64 + i * 16 + l15) * 32 + quad * 8);
                bfr[i] = *(const bf16x8*)(Bs[s] + (wc * 64 + i * 16 + l15) * 32 + quad * 8);
            }
#pragma unroll
            for (int mi = 0; mi < 4; mi++)
#pragma unroll
                for (int ni = 0; ni < 4; ni++)
                    acc[mi][ni] = __builtin_amdgcn_mfma_f32_16x16x32_bf16(af[mi], bfr[ni], acc[mi][ni], 0, 0, 0);
        }
    }

    // epilogue: C/D layout col=lane&15, row=quad*4+reg
#pragma unroll
    for (int ni = 0; ni < 4; ni++) {
        const int gcol = gn0 + wc * 64 + ni * 16 + l15;
        const float bv = bias ? bias[gcol] : 0.0f;
#pragma unroll
        for (int mi = 0; mi < 4; mi++) {
#pragma unroll
            for (int r = 0; r < 4; r++) {
                const int grow = gm0 + wr * 64 + mi * 16 + quad * 4 + r;
                float v = acc[mi][ni][r] + bv;
                if (RELU) v = fmaxf(v, 0.0f);
                if (OUTFP32) {
                    float* C = (float*)Cv + (long long)bz * sC;
                    C[(size_t)grow * ldc + gcol] = v;
                } else {
                    uint16_t* C = (uint16_t*)Cv + (long long)bz * sC;
                    C[(size_t)grow * ldc + gcol] = f2bf(v);
                }
            }
        }
    }
}

// ---------- flat cast fp32 -> bf16, 8 elems/thread ----------
__global__ __launch_bounds__(256)
void cast_f32_bf16(const float* __restrict__ src, uint16_t* __restrict__ dst)
{
    const size_t i = ((size_t)blockIdx.x * 256 + threadIdx.x) * 8;
    float4 f0 = *(const float4*)(src + i);
    float4 f1 = *(const float4*)(src + i + 4);
    uint16_t u[8];
    u[0] = f2bf(f0.x); u[1] = f2bf(f0.y); u[2] = f2bf(f0.z); u[3] = f2bf(f0.w);
    u[4] = f2bf(f1.x); u[5] = f2bf(f1.y); u[6] = f2bf(f1.z); u[7] = f2bf(f1.w);
    *(uint4*)(dst + i) = *(const uint4*)u;
}

// ---------- 2D strided cast fp32 -> bf16 (slice of wide matrix) ----------
__global__ __launch_bounds__(256)
void cast2d_f32_bf16(const float* __restrict__ src, uint16_t* __restrict__ dst,
                     int src_ld, int C)
{
    const size_t i = ((size_t)blockIdx.x * 256 + threadIdx.x) * 8;
    const int r = (int)(i / C), c = (int)(i % C);
    const float* sp = src + (size_t)r * src_ld + c;
    float4 f0 = *(const float4*)sp;
    float4 f1 = *(const float4*)(sp + 4);
    uint16_t u[8];
    u[0] = f2bf(f0.x); u[1] = f2bf(f0.y); u[2] = f2bf(f0.z); u[3] = f2bf(f0.w);
    u[4] = f2bf(f1.x); u[5] = f2bf(f1.y); u[6] = f2bf(f1.z); u[7] = f2bf(f1.w);
    *(uint4*)(dst + i) = *(const uint4*)u;
}

// ---------- transpose fp32 -> bf16: dst[n][k] = bf16(src[k][n]) ----------
__global__ __launch_bounds__(256)
void transpose_f32_to_bf16(const float* __restrict__ src, uint16_t* __restrict__ dst,
                           int src_ld, int dst_ld)
{
    __shared__ uint16_t tile[64 * 65];
    const int k0 = blockIdx.y * 64, n0 = blockIdx.x * 64;
    const int t = threadIdx.x;
#pragma unroll
    for (int i = 0; i < 16; i++) {
        int idx = i * 256 + t;
        int r = idx >> 6, c = idx & 63;
        tile[c * 65 + r] = f2bf(src[(size_t)(k0 + r) * src_ld + n0 + c]);
    }
    __syncthreads();
#pragma unroll
    for (int i = 0; i < 16; i++) {
        int idx = i * 256 + t;
        int n = idx >> 6, k = idx & 63;
        dst[(size_t)(n0 + n) * dst_ld + k0 + k] = tile[n * 65 + k];
    }
}

// ---------- transpose bf16 -> bf16 (batched) ----------
__global__ __launch_bounds__(256)
void transpose_bf16(const uint16_t* __restrict__ src, uint16_t* __restrict__ dst,
                    int src_ld, int dst_ld, long long sS, long long sD)
{
    __shared__ uint16_t tile[64 * 65];
    src += (long long)blockIdx.z * sS;
    dst += (long long)blockIdx.z * sD;
    const int k0 = blockIdx.y * 64, n0 = blockIdx.x * 64;
    const int t = threadIdx.x;
#pragma unroll
    for (int i = 0; i < 16; i++) {
        int idx = i * 256 + t;
        int r = idx >> 6, c = idx & 63;
        tile[c * 65 + r] = src[(size_t)(k0 + r) * src_ld + n0 + c];
    }
    __syncthreads();
#pragma unroll
    for (int i = 0; i < 16; i++) {
        int idx = i * 256 + t;
        int n = idx >> 6, k = idx & 63;
        dst[(size_t)(n0 + n) * dst_ld + k0 + k] = tile[n * 65 + k];
    }
}

// ---------- bias_s[l] = sum_d b2[d] * D2L[d*4096 + l]  (fp32) ----------
__global__ __launch_bounds__(256)
void colbias(const float* __restrict__ b2, const float* __restrict__ D2L,
             float* __restrict__ out)
{
    const int l = blockIdx.x * 256 + threadIdx.x;
    float acc = 0.f;
#pragma unroll 8
    for (int d = 0; d < 1024; d++)
        acc = fmaf(b2[d], D2L[(size_t)d * 4096 + l], acc);
    out[l] = acc;
}

// ---------- masked softmax: bf16 scores + fp32 colbias ->
//            fp32 attention (d_out) + bf16 attention (in-place) ----------
__global__ __launch_bounds__(256)
void softmax_rows(const uint16_t* __restrict__ Sin_, float* __restrict__ Aout,
                  uint16_t* __restrict__ Abf, const float* __restrict__ bs,
                  const int* __restrict__ mask, int L)
{
    const int row = blockIdx.x;
    const int b = row >> 11;                 // L == 2048
    const uint16_t* sp = Sin_ + (size_t)row * L;
    float* op = Aout + (size_t)row * L;
    uint16_t* bp = Abf + (size_t)row * L;
    const int* mrow = mask + (size_t)b * L;
    const int t = threadIdx.x;
    const int c0 = t * 8;

    uint16_t su[8];
    *(uint4*)su = *(const uint4*)(sp + c0);
    float v[8];
    bool mk[8];
    float lmax = -1e30f;
#pragma unroll
    for (int j = 0; j < 8; j++) {
        mk[j] = (mrow[c0 + j] != 0);
        v[j] = bf2f(su[j]) + bs[c0 + j];
        if (mk[j]) lmax = fmaxf(lmax, v[j]);
    }
#pragma unroll
    for (int off = 32; off > 0; off >>= 1)
        lmax = fmaxf(lmax, __shfl_xor(lmax, off, 64));

    __shared__ float redm[4];
    __shared__ float reds[4];
    const int w = t >> 6, lane = t & 63;
    if (lane == 0) redm[w] = lmax;
    __syncthreads();
    lmax = fmaxf(fmaxf(redm[0], redm[1]), fmaxf(redm[2], redm[3]));

    float e[8];
    float lsum = 0.f;
#pragma unroll
    for (int j = 0; j < 8; j++) {
        e[j] = mk[j] ? __expf(v[j] - lmax) : 0.0f;
        lsum += e[j];
    }
#pragma unroll
    for (int off = 32; off > 0; off >>= 1)
        lsum += __shfl_xor(lsum, off, 64);
    if (lane == 0) reds[w] = lsum;
    __syncthreads();
    lsum = reds[0] + reds[1] + reds[2] + reds[3];

    const float inv = 1.0f / lsum;
    uint16_t ub[8];
#pragma unroll
    for (int j = 0; j < 8; j++) {
        v[j] = e[j] * inv;
        ub[j] = f2bf(v[j]);
    }
    *(float4*)(op + c0)     = *(const float4*)(v + 0);
    *(float4*)(op + c0 + 4) = *(const float4*)(v + 4);
    *(uint4*)(bp + c0)      = *(const uint4*)ub;
}

extern "C" void kernel_launch(void* const* d_in, const int* in_sizes, int n_in,
                              void* d_out, int out_size, void* d_ws, size_t ws_size,
                              hipStream_t stream)
{
    const float* x    = (const float*)d_in[0];  // [4,2048,1024]
    const int*   mask = (const int*)d_in[1];    // [4,1,2048]
    const float* W1   = (const float*)d_in[2];  // [1024,1024]
    const float* b1   = (const float*)d_in[3];  // [1024]
    const float* W2   = (const float*)d_in[4];  // [1024,2048]
    const float* b2   = (const float*)d_in[5];  // [2048]
    const float* D2L  = (const float*)d_in[6];  // [1024,4096]

    const int Lr = 2048, D = 1024, M = 4 * Lr;  // 8192
    float* outp = (float*)d_out;                // [8192][1024] fp32
    float* attn = outp + (size_t)M * D;         // [8192][2048] fp32

    // ws layout (bf16 elems), with overlays:
    uint16_t* W1T    = (uint16_t*)d_ws;                  // 1024*1024
    uint16_t* W2vT   = W1T   + 1024 * 1024;              // 1024*1024
    uint16_t* W2DT   = W2vT  + 1024 * 1024;              // 2048*1024
    uint16_t* D2LT   = W2DT  + 2048 * 1024;              // 2048*1024
    uint16_t* W2kbf  = D2LT  + 2048 * 1024;              // 1024*1024
    float*    bias_s = (float*)(W2kbf + 1024 * 1024);    // 2048 fp32
    uint16_t* xbf    = (uint16_t*)(bias_s + 2048);       // 8192*1024  -> Vbuf after h GEMM
    uint16_t* hbuf   = xbf  + (size_t)M * D;             // 8192*1024  -> vT after scores GEMM
    uint16_t* Sbf    = hbuf + (size_t)M * D;             // 8192*2048
    uint16_t* Vbuf   = xbf;   // overlay: x dead once h computed
    uint16_t* vT     = hbuf;  // overlay: h dead once v & scores computed
    // total: 7M + 16M + 16M(Sbf) + ~small = ~39M elems = 78 MB

    dim3 blk(256);

    // input casts / transposes
    cast_f32_bf16<<<dim3(4096), blk, 0, stream>>>(x, xbf);
    transpose_f32_to_bf16<<<dim3(16, 16), blk, 0, stream>>>(W1, W1T, 1024, 1024);
    transpose_f32_to_bf16<<<dim3(16, 16), blk, 0, stream>>>(W2 + 1024, W2vT, 2048, 1024);
    transpose_f32_to_bf16<<<dim3(32, 16), blk, 0, stream>>>(D2L, D2LT, 4096, 1024);
    cast2d_f32_bf16<<<dim3(512), blk, 0, stream>>>(W2, W2kbf, 2048, 1024);
    colbias<<<dim3(8), blk, 0, stream>>>(b2, D2L, bias_s);

    // W2DT[l,e] = sum_d D2LT[l,d] * W2k[e,d]   [2048,1024] K=1024
    gemm_bt<0, 0><<<dim3(8, 16, 1), blk, 0, stream>>>(D2LT, W2kbf, nullptr, W2DT,
        1024, 1024, 1024, 1024, 0, 0, 0);

    // h = relu(x @ W1 + b1)  [8192,1024] K=1024
    gemm_bt<0, 1><<<dim3(8, 64, 1), blk, 0, stream>>>(xbf, W1T, b1, hbuf,
        1024, 1024, 1024, 1024, 0, 0, 0);

    // v = h @ W2v + b2v      [8192,1024] K=1024  (B = 2MB, fits XCD L2)
    gemm_bt<0, 0><<<dim3(8, 64, 1), blk, 0, stream>>>(hbuf, W2vT, b2 + 1024, Vbuf,
        1024, 1024, 1024, 1024, 0, 0, 0);

    // scores = h @ W2D       [8192,2048] K=1024  (B = 4MB, fits XCD L2)
    gemm_bt<0, 0><<<dim3(16, 64, 1), blk, 0, stream>>>(hbuf, W2DT, nullptr, Sbf,
        1024, 1024, 1024, 2048, 0, 0, 0);

    // vT[b][d][m] = v[b][m][d]
    transpose_bf16<<<dim3(16, 32, 4), blk, 0, stream>>>(Vbuf, vT,
        1024, 2048, (long long)2048 * 1024, (long long)1024 * 2048);

    // softmax: bf16 scores + bias_s -> fp32 attn (d_out) + bf16 in-place
    softmax_rows<<<dim3(8192), blk, 0, stream>>>(Sbf, attn, Sbf, bias_s, mask, Lr);

    // output = attn @ v (batched), [2048,1024] per batch, K=2048
    gemm_bt<1, 0><<<dim3(8, 16, 4), blk, 0, stream>>>(Sbf, vT, nullptr, outp,
        2048, 2048, 2048, 1024,
        (long long)2048 * 2048, (long long)1024 * 2048, (long long)2048 * 1024);
}